// Round 3
// baseline (246.390 us; speedup 1.0000x reference)
//
#include <hip/hip_runtime.h>

typedef unsigned long long u64;
typedef unsigned int u32;
typedef float nfloat4 __attribute__((ext_vector_type(4)));   // native vec for nontemporal builtin

static constexpr int NF = 17;      // features per point
static constexpr int BCOL = 9;     // beta column
static constexpr int CCOL = 14;    // first ccoord column (17-3)
static constexpr int CONDCAP = 256;
static constexpr int NPASS = 4;    // grid-wide NMS rounds before k_finish
static constexpr int RPB = 512;    // rows per block in k_filter
static constexpr int MAXIT = 8;    // max per-thread iters in k_pass (8*32*256 = 65536 = P)
static constexpr int LCAP = 7168;  // entries held in LDS by k_finish (7168*20B = 140KB)
static constexpr int FT = 1024;    // k_finish threads
static constexpr int FSLOT = 7;    // LCAP / FT

#define T_B_F ((float)0.2)         // matches numpy float32(0.2)
#define R2_F  ((float)(0.7*0.7))   // matches numpy float32 semantics

__device__ __forceinline__ u64 kmax(u64 a, u64 b){ return a > b ? a : b; }

__device__ __forceinline__ u64 shfl_down_u64(u64 v, int off){
    u32 lo = (u32)v, hi = (u32)(v >> 32);
    lo = __shfl_down(lo, off, 64);
    hi = __shfl_down(hi, off, 64);
    return ((u64)hi << 32) | lo;
}

__device__ __forceinline__ u64 shfl_u64(u64 v, int lane){
    u32 lo = (u32)v, hi = (u32)(v >> 32);
    lo = __shfl(lo, lane, 64);
    hi = __shfl(hi, lane, 64);
    return ((u64)hi << 32) | lo;
}

__device__ __forceinline__ u64 waveReduceMax(u64 k){
    #pragma unroll
    for (int off = 32; off > 0; off >>= 1){
        u64 o = shfl_down_u64(k, off);
        if (o > k) k = o;
    }
    return k;
}

// distance with NO fp contraction — must match numpy (mul,mul,mul,add,add)
__device__ __forceinline__ float dist2(float cx, float cy, float cz,
                                       float rx, float ry, float rz){
    #pragma clang fp contract(off)
    float dx = cx - rx, dy = cy - ry, dz = cz - rz;
    float sx = dx * dx, sy = dy * dy, sz = dz * dz;
    return (sx + sy) + sz;
}

__device__ __forceinline__ u64 makeKey(float beta, u32 idx){
    return ((u64)__float_as_uint(beta) << 32) | (u64)(0xFFFFFFFFu - idx);
}

// ---------------- kernel 0: zero control block (4 KB) ----------------
__global__ void k_init(u32* ws){
    int t = threadIdx.x;
    if (t < 1024) ws[t] = 0;   // argmax[NPASS+1][E], cnt[NPASS+1][E], ncond[E], done
}

// ---------------- kernel 1: zero dout + filter beta>=T_B + per-event argmax ----
__global__ __launch_bounds__(512) void k_filter(
    const float4* __restrict__ x4, float4* __restrict__ out4,
    u64* __restrict__ argmax0, int* __restrict__ cnt0,
    float4* __restrict__ cA, int* __restrict__ iA,
    int P, int chunksPerEvent)
{
    __shared__ float lds[RPB * NF];           // 34816 B
    __shared__ int swc[8], swb[8], sbase;
    __shared__ u64 sred[8];

    int e = blockIdx.x / chunksPerEvent;
    int chunk = blockIdx.x % chunksPerEvent;
    int rowStart = chunk * RPB;
    size_t tile4 = (size_t)blockIdx.x * (RPB * NF / 4);   // 2176 float4 per tile

    float4* lds4 = (float4*)lds;
    const int N4 = RPB * NF / 4;
    nfloat4 z = (nfloat4)0.f;
    for (int i = threadIdx.x; i < N4; i += 512){
        lds4[i] = x4[tile4 + i];
        __builtin_nontemporal_store(z, (nfloat4*)&out4[tile4 + i]);  // zero dout, bypass caches
    }
    __syncthreads();

    int tid = threadIdx.x, lid = tid & 63, wid = tid >> 6;
    float be = lds[tid*NF+BCOL];
    float cx = lds[tid*NF+CCOL], cy = lds[tid*NF+CCOL+1], cz = lds[tid*NF+CCOL+2];
    bool kp = (be >= T_B_F);
    u64 bal = __ballot(kp);
    int wcnt = __popcll(bal);
    u64 lk = kp ? makeKey(be, (u32)(rowStart + tid)) : 0;
    u64 kw = waveReduceMax(lk);
    if (lid == 0){ swc[wid] = wcnt; sred[wid] = kw; }
    __syncthreads();
    if (tid == 0){
        int tot = 0;
        for (int w = 0; w < 8; w++){ swb[w] = tot; tot += swc[w]; }
        sbase = tot ? atomicAdd(&cnt0[e], tot) : 0;      // 1 returning atomic / block
        u64 m = sred[0];
        for (int i = 1; i < 8; i++) m = kmax(m, sred[i]);
        if (m) atomicMax(&argmax0[e], m);                // fire-and-forget
    }
    __syncthreads();
    if (kp){
        int pos = sbase + swb[wid] + __popcll(bal & ((1ull << lid) - 1));
        size_t eoff = (size_t)e * P;
        cA[eoff + pos] = make_float4(cx, cy, cz, be);
        iA[eoff + pos] = rowStart + tid;
    }
}

// ---------------- kernel 2: one grid-wide NMS round; ONE atomic per block ------
__global__ __launch_bounds__(256) void k_pass(
    const float* __restrict__ x,
    const float4* __restrict__ cIn, const int* __restrict__ iIn,
    float4* __restrict__ cOut, int* __restrict__ iOut,
    const u64* __restrict__ argmaxIn, u64* __restrict__ argmaxOut,
    const int* __restrict__ cntIn, int* __restrict__ cntOut,
    int* __restrict__ ncond, int* __restrict__ condlist,
    int P, int blocksPerEvent)
{
    __shared__ int swc[4], swb[4], sbase;
    __shared__ u64 sred[4];

    int e = blockIdx.x / blocksPerEvent;
    int c = blockIdx.x % blocksPerEvent;
    u64 key = argmaxIn[e];
    float betaRef = __uint_as_float((u32)(key >> 32));
    if (!(betaRef >= T_B_F)) return;   // event finished (uniform across its blocks)
    u32 refIdx = 0xFFFFFFFFu - (u32)(key & 0xFFFFFFFFu);
    if (c == 0 && threadIdx.x == 0){
        int s = atomicAdd(&ncond[e], 1);
        if (s < CONDCAP) condlist[e * CONDCAP + s] = (int)refIdx;
    }
    int n = cntIn[e];
    if (c * 256 >= n) return;          // whole block out of range (uniform)
    size_t rbase = ((size_t)e * P + refIdx) * NF;
    float rx = x[rbase + CCOL], ry = x[rbase + CCOL + 1], rz = x[rbase + CCOL + 2];

    int tid = threadIdx.x, lid = tid & 63, wid = tid >> 6;
    size_t eoff = (size_t)e * P;
    int stride = blocksPerEvent * 256;

    float4 cc[MAXIT]; int ix[MAXIT]; bool kp[MAXIT]; u64 bal[MAXIT];
    int wcnt = 0;
    u64 lk = 0;
    #pragma unroll
    for (int k = 0; k < MAXIT; k++){
        int i = c * 256 + tid + k * stride;
        bool inb = i < n;
        int ii = inb ? i : 0;
        cc[k] = cIn[eoff + ii];
        ix[k] = iIn[eoff + ii];
        float d2 = dist2(cc[k].x, cc[k].y, cc[k].z, rx, ry, rz);
        kp[k] = inb && !(d2 <= R2_F);
        bal[k] = __ballot(kp[k]);
        wcnt += __popcll(bal[k]);
        if (kp[k]) lk = kmax(lk, makeKey(cc[k].w, (u32)ix[k]));
    }
    u64 kw = waveReduceMax(lk);
    if (lid == 0){ swc[wid] = wcnt; sred[wid] = kw; }
    __syncthreads();
    if (tid == 0){
        int tot = 0;
        for (int w = 0; w < 4; w++){ swb[w] = tot; tot += swc[w]; }
        sbase = tot ? atomicAdd(&cntOut[e], tot) : 0;
        u64 m = sred[0];
        for (int i = 1; i < 4; i++) m = kmax(m, sred[i]);
        if (m) atomicMax(&argmaxOut[e], m);
    }
    __syncthreads();
    int pos = sbase + swb[wid];
    u64 lm = (1ull << lid) - 1;
    #pragma unroll
    for (int k = 0; k < MAXIT; k++){
        if (kp[k]){
            int p_ = pos + __popcll(bal[k] & lm);
            cOut[eoff + p_] = cc[k];
            iOut[eoff + p_] = ix[k];
        }
        pos += __popcll(bal[k]);
    }
}

// ---------------- kernel 3: per-event finish. Global rounds until list fits in
// LDS, then all remaining NMS rounds run LDS-resident with in-place compaction
// and up to 4 greedy accepts per round (exact: global top-4 walk). Fuses the
// old k_out epilogue (condensate-row scatter + row_splits by last block).
__global__ __launch_bounds__(1024) void k_finish(
    const float* __restrict__ x,
    float4* cA, int* iA, float4* cB, int* iB,
    const u64* __restrict__ argmaxN, const int* __restrict__ cntN,
    int* __restrict__ ncond, const int* __restrict__ condlistG,
    int* __restrict__ done, float* __restrict__ out, int P, int E)
{
    __shared__ u64 skey[LCAP];                 // 57344 B
    __shared__ float sx[LCAP], sy[LCAP], sz[LCAP];   // 86016 B
    __shared__ u64 sred[16];
    __shared__ u64 wtopk[16*4];
    __shared__ int wtopp[16*4];
    __shared__ int condL[CONDCAP];
    __shared__ float refs[4][3];
    __shared__ int scnt, snc, snacc;
    __shared__ u64 skeyb;
    __shared__ float srefc[3];

    int e = blockIdx.x;
    int tid = threadIdx.x, lid = tid & 63, wid = tid >> 6;
    int n = cntN[e];
    u64 key = argmaxN[e];
    float4* cIn = cA + (size_t)e * P; int* iIn = iA + (size_t)e * P;
    float4* cOut = cB + (size_t)e * P; int* iOut = iB + (size_t)e * P;

    if (tid == 0) snc = ncond[e];
    for (int i = tid; i < CONDCAP; i += FT) condL[i] = condlistG[e * CONDCAP + i];
    __syncthreads();

    // ---- phase 1: global-memory rounds while list too big for LDS ----
    while (n > LCAP){
        float betaRef = __uint_as_float((u32)(key >> 32));
        if (!(betaRef >= T_B_F)) break;
        u32 refIdx = 0xFFFFFFFFu - (u32)(key & 0xFFFFFFFFu);
        if (tid == 0){
            if (snc < CONDCAP) condL[snc] = (int)refIdx;
            snc++;
            size_t rbase = ((size_t)e * P + refIdx) * NF;
            srefc[0] = x[rbase + CCOL];
            srefc[1] = x[rbase + CCOL + 1];
            srefc[2] = x[rbase + CCOL + 2];
            scnt = 0;
        }
        __syncthreads();
        float rx = srefc[0], ry = srefc[1], rz = srefc[2];
        u64 localKey = 0;
        for (int i = tid; i < n; i += FT){
            float4 cc = cIn[i]; int idx = iIn[i];
            float d2 = dist2(cc.x, cc.y, cc.z, rx, ry, rz);
            bool keep = !(d2 <= R2_F);
            u64 bal = __ballot(keep);
            int cw = __popcll(bal);
            int b_ = 0;
            if (lid == 0) b_ = cw ? atomicAdd(&scnt, cw) : 0;
            b_ = __shfl(b_, 0, 64);
            if (keep){
                int pos = b_ + __popcll(bal & ((1ull << lid) - 1));
                cOut[pos] = cc; iOut[pos] = idx;
                localKey = kmax(localKey, makeKey(cc.w, (u32)idx));
            }
        }
        u64 kw = waveReduceMax(localKey);
        if (lid == 0) sred[wid] = kw;
        __syncthreads();
        if (tid == 0){
            u64 m = 0;
            for (int i = 0; i < 16; i++) m = kmax(m, sred[i]);
            skeyb = m;
        }
        __syncthreads();
        key = skeyb; n = scnt;
        { float4* t = cIn; cIn = cOut; cOut = t; }
        { int* t = iIn; iIn = iOut; iOut = t; }
        __syncthreads();
    }

    // ---- phase 2: LDS-resident rounds ----
    float betaRef0 = __uint_as_float((u32)(key >> 32));
    if (betaRef0 >= T_B_F && n > 0){
        for (int i = tid; i < n; i += FT){
            float4 cc = cIn[i]; int idx = iIn[i];
            skey[i] = makeKey(cc.w, (u32)idx);
            sx[i] = cc.x; sy[i] = cc.y; sz[i] = cc.z;
        }
        __syncthreads();

        while (n > 0){
            // (S0) per-wave top-4 (key,pos), desc order
            u64 myk[FSLOT]; int myp[FSLOT]; int mc = 0;
            for (int i = tid; i < n; i += FT){ myk[mc] = skey[i]; myp[mc] = i; mc++; }
            u64 excl = ~0ull;
            #pragma unroll
            for (int j = 0; j < 4; j++){
                u64 lk = 0; int lp = 0;
                #pragma unroll
                for (int k = 0; k < FSLOT; k++)
                    if (k < mc && myk[k] < excl && myk[k] > lk){ lk = myk[k]; lp = myp[k]; }
                #pragma unroll
                for (int off = 32; off > 0; off >>= 1){
                    u64 ok = shfl_down_u64(lk, off);
                    int op = __shfl_down(lp, off, 64);
                    if (ok > lk){ lk = ok; lp = op; }
                }
                if (lid == 0){ wtopk[wid*4 + j] = lk; wtopp[wid*4 + j] = lp; }
                excl = shfl_u64(lk, 0);     // broadcast selected key
            }
            __syncthreads();                // B1

            // (S1) thread 0: merge 64 -> global top-4 walk, greedy accept
            if (tid == 0){
                int na = 0;
                u64 ex = ~0ull;
                for (int rsel = 0; rsel < 4; rsel++){
                    u64 m = 0; int mp = 0;
                    for (int t = 0; t < 64; t++){
                        u64 kk2 = wtopk[t];
                        if (kk2 < ex && kk2 > m){ m = kk2; mp = wtopp[t]; }
                    }
                    if (m == 0) break;
                    ex = m;
                    float cx2 = sx[mp], cy2 = sy[mp], cz2 = sz[mp];
                    bool ok = true;
                    #pragma unroll
                    for (int a = 0; a < 4; a++)
                        if (a < na && dist2(cx2, cy2, cz2,
                                            refs[a][0], refs[a][1], refs[a][2]) <= R2_F)
                            ok = false;
                    if (ok){
                        u32 idx2 = 0xFFFFFFFFu - (u32)(m & 0xFFFFFFFFu);
                        if (snc < CONDCAP) condL[snc] = (int)idx2;
                        snc++;
                        refs[na][0] = cx2; refs[na][1] = cy2; refs[na][2] = cz2;
                        na++;
                    }
                }
                snacc = na; scnt = 0;
            }
            __syncthreads();                // B2

            // (S2) filter vs the <=4 refs accepted this round; stash + positions
            int na = snacc;
            float rx_[4], ry_[4], rz_[4];
            #pragma unroll
            for (int a = 0; a < 4; a++){ rx_[a] = refs[a][0]; ry_[a] = refs[a][1]; rz_[a] = refs[a][2]; }
            u64 kk[FSLOT]; float xx[FSLOT], yy[FSLOT], zz[FSLOT];
            bool kp[FSLOT]; u64 bal[FSLOT];
            int wcnt = 0;
            #pragma unroll
            for (int k = 0; k < FSLOT; k++){
                int i = tid + k * FT;
                bool inb = i < n;
                int ii = inb ? i : 0;
                kk[k] = skey[ii]; xx[k] = sx[ii]; yy[k] = sy[ii]; zz[k] = sz[ii];
                bool keep = inb;
                #pragma unroll
                for (int a = 0; a < 4; a++)
                    if (a < na && dist2(xx[k], yy[k], zz[k], rx_[a], ry_[a], rz_[a]) <= R2_F)
                        keep = false;
                kp[k] = keep;
                bal[k] = __ballot(keep);
                wcnt += __popcll(bal[k]);
            }
            int wb = 0;
            if (lid == 0) wb = wcnt ? atomicAdd(&scnt, wcnt) : 0;
            wb = __shfl(wb, 0, 64);
            __syncthreads();                // B3: all LDS reads done

            // (S3) in-place compaction writes
            int posr = wb;
            u64 lm = (1ull << lid) - 1;
            #pragma unroll
            for (int k = 0; k < FSLOT; k++){
                if (kp[k]){
                    int p_ = posr + __popcll(bal[k] & lm);
                    skey[p_] = kk[k]; sx[p_] = xx[k]; sy[p_] = yy[k]; sz[p_] = zz[k];
                }
                posr += __popcll(bal[k]);
            }
            __syncthreads();                // B4
            n = scnt;
        }
    }
    __syncthreads();

    // ---- epilogue (old k_out fused): scatter condensate rows of this event ----
    int ncT = snc;
    int ncc = ncT > CONDCAP ? CONDCAP : ncT;
    for (int i = tid; i < ncc * NF; i += FT){
        int j = i / NF, f = i - j * NF;
        int row = condL[j];
        size_t base = ((size_t)e * P + row) * NF;
        out[base + f] = x[base + f];
    }
    if (tid == 0){
        ncond[e] = ncT;
        __threadfence();
        int r = atomicAdd(done, 1);
        if (r == E - 1){                    // last block writes row_splits
            size_t ob = (size_t)E * P * NF;
            int s = 0;
            out[ob] = 0.0f;
            for (int i = 0; i < E; i++){
                s += atomicAdd(&ncond[i], 0);   // device-scope read
                out[ob + i + 1] = (float)s;
            }
        }
    }
}

extern "C" void kernel_launch(void* const* d_in, const int* in_sizes, int n_in,
                              void* d_out, int out_size, void* d_ws, size_t ws_size,
                              hipStream_t stream) {
    const float* x = (const float*)d_in[0];
    int N = in_sizes[0] / NF;
    int E = in_sizes[1] - 1;
    int P = N / E;
    float* out = (float*)d_out;
    char* ws = (char*)d_ws;

    // ws layout (first 4 KB zeroed by k_init)
    u64* argmax = (u64*)ws;                         // [NPASS+1][E]
    int* cnt    = (int*)(ws + 1024);                // [NPASS+1][E]
    int* ncond  = (int*)(ws + 2048);                // [E]
    int* done   = (int*)(ws + 2560);                // [1]
    int* condlist = (int*)(ws + 4096);              // [E][CONDCAP]
    size_t listOff = 32768;
    size_t listElems = (size_t)E * P;
    float4* cA = (float4*)(ws + listOff);
    float4* cB = (float4*)(ws + listOff + listElems * 16);
    int* iA = (int*)(ws + listOff + listElems * 32);
    int* iB = (int*)(ws + listOff + listElems * 36);

    k_init<<<1, 1024, 0, stream>>>((u32*)ws);

    int chunksPerEvent = P / RPB;                   // 128
    k_filter<<<E * chunksPerEvent, 512, 0, stream>>>(
        (const float4*)x, (float4*)out, argmax, cnt, cA, iA, P, chunksPerEvent);

    int bpe = 32;                                   // 32*256*MAXIT = 65536 = P coverage
    float4* cs[2] = {cA, cB};
    int* is[2] = {iA, iB};
    for (int r = 0; r < NPASS; r++){
        k_pass<<<E * bpe, 256, 0, stream>>>(
            x, cs[r & 1], is[r & 1], cs[(r + 1) & 1], is[(r + 1) & 1],
            argmax + r * E, argmax + (r + 1) * E,
            cnt + r * E, cnt + (r + 1) * E,
            ncond, condlist, P, bpe);
    }

    // NPASS even -> current list is back in cA
    k_finish<<<E, 1024, 0, stream>>>(
        x, cA, iA, cB, iB, argmax + NPASS * E, cnt + NPASS * E,
        ncond, condlist, done, out, P, E);
}

// Round 4
// 227.958 us; speedup vs baseline: 1.0809x; 1.0809x over previous
//
#include <hip/hip_runtime.h>

typedef unsigned long long u64;
typedef unsigned int u32;

static constexpr int NF = 17;      // features per point
static constexpr int BCOL = 9;     // beta column
static constexpr int CCOL = 14;    // first ccoord column (17-3)
static constexpr int CONDCAP = 1024;
static constexpr int RPB = 512;    // rows per block in k_filter
static constexpr int LCAP = 7168;  // entries held in LDS by k_finish (143KB)
static constexpr int FT = 1024;    // k_finish threads

#define T_B_F ((float)0.2)         // matches numpy float32(0.2)
#define R2_F  ((float)(0.7*0.7))   // matches numpy float32 semantics

__device__ __forceinline__ u64 kmax(u64 a, u64 b){ return a > b ? a : b; }

__device__ __forceinline__ u64 shfl_down_u64(u64 v, int off){
    u32 lo = (u32)v, hi = (u32)(v >> 32);
    lo = __shfl_down(lo, off, 64);
    hi = __shfl_down(hi, off, 64);
    return ((u64)hi << 32) | lo;
}

__device__ __forceinline__ u64 shfl_u64(u64 v, int lane){
    u32 lo = (u32)v, hi = (u32)(v >> 32);
    lo = __shfl(lo, lane, 64);
    hi = __shfl(hi, lane, 64);
    return ((u64)hi << 32) | lo;
}

__device__ __forceinline__ u64 waveReduceMax(u64 k){
    #pragma unroll
    for (int off = 32; off > 0; off >>= 1){
        u64 o = shfl_down_u64(k, off);
        if (o > k) k = o;
    }
    return k;
}

// distance with NO fp contraction — must match numpy (mul,mul,mul,add,add)
__device__ __forceinline__ float dist2(float cx, float cy, float cz,
                                       float rx, float ry, float rz){
    #pragma clang fp contract(off)
    float dx = cx - rx, dy = cy - ry, dz = cz - rz;
    float sx = dx * dx, sy = dy * dy, sz = dz * dz;
    return (sx + sy) + sz;
}

__device__ __forceinline__ u64 makeKey(float beta, u32 idx){
    return ((u64)__float_as_uint(beta) << 32) | (u64)(0xFFFFFFFFu - idx);
}

// ---------------- kernel 0: zero control block (4 KB) ----------------
__global__ void k_init(u32* ws){
    int t = threadIdx.x;
    if (t < 1024) ws[t] = 0;   // argmax[E], cnt[E], ncond[E], done
}

// ---------------- kernel 1: zero dout + filter beta>=T_B + per-event argmax ----
__global__ __launch_bounds__(512) void k_filter(
    const float4* __restrict__ x4, float4* __restrict__ out4,
    u64* __restrict__ argmax0, int* __restrict__ cnt0,
    float4* __restrict__ cA, int* __restrict__ iA,
    int P, int chunksPerEvent)
{
    __shared__ float lds[RPB * NF];           // 34816 B
    __shared__ int swc[8], swb[8], sbase;
    __shared__ u64 sred[8];

    int e = blockIdx.x / chunksPerEvent;
    int chunk = blockIdx.x % chunksPerEvent;
    int rowStart = chunk * RPB;
    size_t tile4 = (size_t)blockIdx.x * (RPB * NF / 4);   // 2176 float4 per tile

    float4* lds4 = (float4*)lds;
    const int N4 = RPB * NF / 4;
    float4 z = make_float4(0.f, 0.f, 0.f, 0.f);
    for (int i = threadIdx.x; i < N4; i += 512){
        lds4[i] = x4[tile4 + i];
        out4[tile4 + i] = z;                   // fused zero of dout
    }
    __syncthreads();

    int tid = threadIdx.x, lid = tid & 63, wid = tid >> 6;
    float be = lds[tid*NF+BCOL];
    float cx = lds[tid*NF+CCOL], cy = lds[tid*NF+CCOL+1], cz = lds[tid*NF+CCOL+2];
    bool kp = (be >= T_B_F);
    u64 bal = __ballot(kp);
    int wcnt = __popcll(bal);
    u64 lk = kp ? makeKey(be, (u32)(rowStart + tid)) : 0;
    u64 kw = waveReduceMax(lk);
    if (lid == 0){ swc[wid] = wcnt; sred[wid] = kw; }
    __syncthreads();
    if (tid == 0){
        int tot = 0;
        for (int w = 0; w < 8; w++){ swb[w] = tot; tot += swc[w]; }
        sbase = tot ? atomicAdd(&cnt0[e], tot) : 0;      // 1 returning atomic / block
        u64 m = sred[0];
        for (int i = 1; i < 8; i++) m = kmax(m, sred[i]);
        if (m) atomicMax(&argmax0[e], m);                // fire-and-forget
    }
    __syncthreads();
    if (kp){
        int pos = sbase + swb[wid] + __popcll(bal & ((1ull << lid) - 1));
        size_t eoff = (size_t)e * P;
        cA[eoff + pos] = make_float4(cx, cy, cz, be);
        iA[eoff + pos] = rowStart + tid;
    }
}

// ---------------- kernel 2: per-event full NMS. One block per event.
// Phase 1: block-wide global compaction rounds while n > LCAP.
// Phase 2: single-wave LDS-resident rounds (fused kill+compact+argmax, no barriers).
// Epilogue: scatter condensate rows + row_splits (last block).
__global__ __launch_bounds__(1024) void k_finish(
    const float* __restrict__ x,
    float4* cA, int* iA, float4* cB, int* iB,
    const u64* __restrict__ argmax0, const int* __restrict__ cnt0,
    int* __restrict__ ncond, int* __restrict__ done,
    float* __restrict__ out, int P, int E)
{
    __shared__ u64 skey[LCAP];                       // 57344 B
    __shared__ float sx[LCAP], sy[LCAP], sz[LCAP];   // 86016 B
    __shared__ u64 sred[16];
    __shared__ int condL[CONDCAP];                   // 4096 B
    __shared__ int scnt, snc;
    __shared__ u64 skeyb;
    __shared__ float srefc[3];

    int e = blockIdx.x;
    int tid = threadIdx.x, lid = tid & 63, wid = tid >> 6;
    int n = cnt0[e];
    u64 key = argmax0[e];
    float4* cIn = cA + (size_t)e * P; int* iIn = iA + (size_t)e * P;
    float4* cOut = cB + (size_t)e * P; int* iOut = iB + (size_t)e * P;

    if (tid == 0) snc = 0;
    __syncthreads();

    // ---- phase 1: global-memory compaction rounds while list too big for LDS ----
    while (n > LCAP){
        float betaRef = __uint_as_float((u32)(key >> 32));
        if (!(betaRef >= T_B_F)) break;
        u32 refIdx = 0xFFFFFFFFu - (u32)(key & 0xFFFFFFFFu);
        if (tid == 0){
            if (snc < CONDCAP) condL[snc] = (int)refIdx;
            snc++;
            size_t rbase = ((size_t)e * P + refIdx) * NF;
            srefc[0] = x[rbase + CCOL];
            srefc[1] = x[rbase + CCOL + 1];
            srefc[2] = x[rbase + CCOL + 2];
            scnt = 0;
        }
        __syncthreads();
        float rx = srefc[0], ry = srefc[1], rz = srefc[2];
        u64 localKey = 0;
        for (int i = tid; i < n; i += FT){
            float4 cc = cIn[i]; int idx = iIn[i];
            float d2 = dist2(cc.x, cc.y, cc.z, rx, ry, rz);
            bool keep = !(d2 <= R2_F);
            u64 bal = __ballot(keep);
            int cw = __popcll(bal);
            int b_ = 0;
            if (lid == 0) b_ = cw ? atomicAdd(&scnt, cw) : 0;
            b_ = __shfl(b_, 0, 64);
            if (keep){
                int pos = b_ + __popcll(bal & ((1ull << lid) - 1));
                cOut[pos] = cc; iOut[pos] = idx;
                localKey = kmax(localKey, makeKey(cc.w, (u32)idx));
            }
        }
        u64 kw = waveReduceMax(localKey);
        if (lid == 0) sred[wid] = kw;
        __syncthreads();
        if (tid == 0){
            u64 m = 0;
            for (int i = 0; i < 16; i++) m = kmax(m, sred[i]);
            skeyb = m;
        }
        __syncthreads();
        key = skeyb; n = scnt;
        { float4* t = cIn; cIn = cOut; cOut = t; }
        { int* t = iIn; iIn = iOut; iOut = t; }
        __syncthreads();
    }

    // ---- phase 2: LDS-resident, single-wave rounds ----
    float betaRef0 = __uint_as_float((u32)(key >> 32));
    if (betaRef0 >= T_B_F && n > 0){
        for (int i = tid; i < n; i += FT){          // stage with all 16 waves
            float4 cc = cIn[i]; int idx = iIn[i];
            skey[i] = makeKey(cc.w, (u32)idx);
            sx[i] = cc.x; sy[i] = cc.y; sz[i] = cc.z;
        }
        __syncthreads();

        if (wid == 0){
            int snc_l = snc;
            int mp = -1;                             // LDS pos of current ref (-1: from global)
            while (true){
                float betaRef = __uint_as_float((u32)(key >> 32));
                if (!(betaRef >= T_B_F)) break;
                u32 refIdx = 0xFFFFFFFFu - (u32)(key & 0xFFFFFFFFu);
                if (lid == 0 && snc_l < CONDCAP) condL[snc_l] = (int)refIdx;
                snc_l++;
                float rx, ry, rz;
                if (mp >= 0){ rx = sx[mp]; ry = sy[mp]; rz = sz[mp]; }
                else {
                    size_t rbase = ((size_t)e * P + refIdx) * NF;
                    rx = x[rbase + CCOL]; ry = x[rbase + CCOL + 1]; rz = x[rbase + CCOL + 2];
                }
                // fused kill + in-place compact + argmax, one pass, wave-lockstep.
                // Writes of chunk i0 go to pos < i0+64 and reads of later chunks are
                // at i >= i0+64, and within a chunk all lane reads precede writes.
                u64 bk = 0; int bp = -1;
                int alive = 0;
                for (int i0 = 0; i0 < n; i0 += 64){
                    int i = i0 + lid;
                    bool inb = i < n;
                    int ii = inb ? i : 0;
                    u64 k = skey[ii];
                    float xx = sx[ii], yy = sy[ii], zz = sz[ii];
                    float d2 = dist2(xx, yy, zz, rx, ry, rz);
                    bool keep = inb && !(d2 <= R2_F);
                    u64 b = __ballot(keep);
                    if (keep){
                        int pos = alive + __popcll(b & ((1ull << lid) - 1));
                        skey[pos] = k; sx[pos] = xx; sy[pos] = yy; sz[pos] = zz;
                        if (k > bk){ bk = k; bp = pos; }
                    }
                    alive += __popcll(b);
                }
                #pragma unroll
                for (int off = 32; off > 0; off >>= 1){
                    u64 ok = shfl_down_u64(bk, off);
                    int op = __shfl_down(bp, off, 64);
                    if (ok > bk){ bk = ok; bp = op; }
                }
                key = shfl_u64(bk, 0);
                mp = __shfl(bp, 0, 64);
                n = alive;
            }
            if (lid == 0) snc = snc_l;
        }
    }
    __syncthreads();

    // ---- epilogue: scatter condensate rows of this event ----
    int ncT = snc;
    int ncc = ncT > CONDCAP ? CONDCAP : ncT;
    for (int i = tid; i < ncc * NF; i += FT){
        int j = i / NF, f = i - j * NF;
        int row = condL[j];
        size_t base = ((size_t)e * P + row) * NF;
        out[base + f] = x[base + f];
    }
    if (tid == 0){
        ncond[e] = ncT;
        __threadfence();
        int r = atomicAdd(done, 1);
        if (r == E - 1){                    // last block writes row_splits
            size_t ob = (size_t)E * P * NF;
            int s = 0;
            out[ob] = 0.0f;
            for (int i = 0; i < E; i++){
                s += atomicAdd(&ncond[i], 0);   // device-scope read
                out[ob + i + 1] = (float)s;
            }
        }
    }
}

extern "C" void kernel_launch(void* const* d_in, const int* in_sizes, int n_in,
                              void* d_out, int out_size, void* d_ws, size_t ws_size,
                              hipStream_t stream) {
    const float* x = (const float*)d_in[0];
    int N = in_sizes[0] / NF;
    int E = in_sizes[1] - 1;
    int P = N / E;
    float* out = (float*)d_out;
    char* ws = (char*)d_ws;

    // ws layout (first 4 KB zeroed by k_init)
    u64* argmax = (u64*)ws;                         // [E]
    int* cnt    = (int*)(ws + 1024);                // [E]
    int* ncond  = (int*)(ws + 2048);                // [E]
    int* done   = (int*)(ws + 2560);                // [1]
    size_t listOff = 32768;
    size_t listElems = (size_t)E * P;
    float4* cA = (float4*)(ws + listOff);
    float4* cB = (float4*)(ws + listOff + listElems * 16);
    int* iA = (int*)(ws + listOff + listElems * 32);
    int* iB = (int*)(ws + listOff + listElems * 36);

    k_init<<<1, 1024, 0, stream>>>((u32*)ws);

    int chunksPerEvent = P / RPB;                   // 128
    k_filter<<<E * chunksPerEvent, 512, 0, stream>>>(
        (const float4*)x, (float4*)out, argmax, cnt, cA, iA, P, chunksPerEvent);

    k_finish<<<E, 1024, 0, stream>>>(
        x, cA, iA, cB, iB, argmax, cnt, ncond, done, out, P, E);
}